// Round 1
// baseline (580.771 us; speedup 1.0000x reference)
//
#include <hip/hip_runtime.h>
#include <math.h>

#define N 8192
#define D 256
#define BM 16          // rows per neighbor-block
#define CJ 4           // columns per thread per tile
#define NTHREADS 256
#define NCHUNK 4
#define CHUNK (N / NCHUNK)        // 2048 columns per block
#define TILEW (CJ * NTHREADS)     // 1024 columns per tile

constexpr float MARGIN = 0.3f;
constexpr float EPS_PAIR = 1e-6f;

// ---------- helpers ----------
__device__ __forceinline__ bool lessVI(float v, int i, float w, int j) {
  return (v < w) || (v == w && i < j);
}

// merge sorted pair (w1,q1,w2,q2) into running sorted top-2 (v1,i1,v2,i2)
__device__ __forceinline__ void mergePair(float& v1, int& i1, float& v2, int& i2,
                                          float w1, int q1, float w2, int q2) {
  if (lessVI(w1, q1, v1, i1)) {
    bool b = lessVI(v1, i1, w2, q2);
    float nv2 = b ? v1 : w2;
    int   ni2 = b ? i1 : q2;
    v1 = w1; i1 = q1; v2 = nv2; i2 = ni2;
  } else if (lessVI(w1, q1, v2, i2)) {
    v2 = w1; i2 = q1;
  }
}

// ---------- kernel 0: transpose inputs -> inputsT [D][N] ----------
__global__ void transpose_kernel(const float* __restrict__ in, float* __restrict__ outT) {
  __shared__ float tile[32][33];
  int jBase = blockIdx.x * 32;   // row index in 'in'
  int kBase = blockIdx.y * 32;   // col index in 'in'
  int tx = threadIdx.x;          // 0..31
  int ty = threadIdx.y;          // 0..7
#pragma unroll
  for (int r = ty; r < 32; r += 8)
    tile[r][tx] = in[(size_t)(jBase + r) * D + kBase + tx];
  __syncthreads();
#pragma unroll
  for (int r = ty; r < 32; r += 8)
    outT[(size_t)(kBase + r) * N + jBase + tx] = tile[tx][r];
}

// ---------- kernel 1: row squared norms ----------
__global__ void rowsq_kernel(const float* __restrict__ in, float* __restrict__ sq) {
  int row  = blockIdx.x * 4 + (threadIdx.x >> 6);
  int lane = threadIdx.x & 63;
  float4 v = ((const float4*)(in + (size_t)row * D))[lane];
  float s = v.x * v.x + v.y * v.y + v.z * v.z + v.w * v.w;
#pragma unroll
  for (int m = 32; m; m >>= 1) s += __shfl_xor(s, m);
  if (lane == 0) sq[row] = s;
}

// ---------- kernel 2: fused Gram + per-row top-2-min (partial per column chunk) ----------
__global__ __launch_bounds__(NTHREADS) void neighbor_kernel(
    const float* __restrict__ A, const float* __restrict__ AT,
    const float* __restrict__ sq,
    float* __restrict__ pv1, int* __restrict__ pi1,
    float* __restrict__ pv2, int* __restrict__ pi2) {
  __shared__ float Atile[BM][D];
  __shared__ float wv1s[4][BM], wv2s[4][BM];
  __shared__ int   wi1s[4][BM], wi2s[4][BM];
  __shared__ float bv1[BM], bv2[BM];
  __shared__ int   bi1[BM], bi2[BM];

  const int t = threadIdx.x;
  const int lane = t & 63;
  const int wave = t >> 6;
  const int rowBase = blockIdx.x * BM;
  const int colBase = blockIdx.y * CHUNK;

  // load A tile (BM x D), coalesced
#pragma unroll
  for (int it = 0; it < BM * D / NTHREADS; ++it) {
    int idx = it * NTHREADS + t;
    Atile[idx >> 8][idx & (D - 1)] = A[(size_t)rowBase * D + idx];
  }
  if (t < BM) { bv1[t] = INFINITY; bv2[t] = INFINITY; bi1[t] = 0x7fffffff; bi2[t] = 0x7fffffff; }
  __syncthreads();

  for (int jt = colBase; jt < colBase + CHUNK; jt += TILEW) {
    int j[CJ];
#pragma unroll
    for (int c = 0; c < CJ; ++c) j[c] = jt + c * NTHREADS + t;

    float acc[BM][CJ];
#pragma unroll
    for (int r = 0; r < BM; ++r)
#pragma unroll
      for (int c = 0; c < CJ; ++c) acc[r][c] = 0.f;

    for (int k = 0; k < D; k += 4) {
      float b[4][CJ];
#pragma unroll
      for (int kk = 0; kk < 4; ++kk)
#pragma unroll
        for (int c = 0; c < CJ; ++c)
          b[kk][c] = AT[(size_t)(k + kk) * N + j[c]];
#pragma unroll
      for (int r = 0; r < BM; ++r) {
        float4 a = *(const float4*)&Atile[r][k];
#pragma unroll
        for (int c = 0; c < CJ; ++c)
          acc[r][c] = fmaf(a.x, b[0][c],
                      fmaf(a.y, b[1][c],
                      fmaf(a.z, b[2][c],
                      fmaf(a.w, b[3][c], acc[r][c]))));
      }
    }

    float sqv[CJ];
#pragma unroll
    for (int c = 0; c < CJ; ++c) sqv[c] = sq[j[c]];

#pragma unroll
    for (int r = 0; r < BM; ++r) {
      int gi = rowBase + r;
      float v1 = INFINITY, v2 = INFINITY;
      int i1 = 0x7fffffff, i2 = 0x7fffffff;
#pragma unroll
      for (int c = 0; c < CJ; ++c) {
        float s = fmaf(-2.f, acc[r][c], sqv[c]);   // dist^2 - sq[i], monotone per row
        int jj = j[c];
        if (jj == gi) s = INFINITY;                // exclude self
        if (lessVI(s, jj, v1, i1)) { v2 = v1; i2 = i1; v1 = s; i1 = jj; }
        else if (lessVI(s, jj, v2, i2)) { v2 = s; i2 = jj; }
      }
      // wave butterfly top-2
#pragma unroll
      for (int m = 1; m < 64; m <<= 1) {
        float w1 = __shfl_xor(v1, m); int q1 = __shfl_xor(i1, m);
        float w2 = __shfl_xor(v2, m); int q2 = __shfl_xor(i2, m);
        mergePair(v1, i1, v2, i2, w1, q1, w2, q2);
      }
      if (lane == 0) { wv1s[wave][r] = v1; wi1s[wave][r] = i1; wv2s[wave][r] = v2; wi2s[wave][r] = i2; }
    }
    __syncthreads();
    if (t < BM) {
      float v1 = bv1[t]; int i1 = bi1[t]; float v2 = bv2[t]; int i2 = bi2[t];
#pragma unroll
      for (int w = 0; w < 4; ++w)
        mergePair(v1, i1, v2, i2, wv1s[w][t], wi1s[w][t], wv2s[w][t], wi2s[w][t]);
      bv1[t] = v1; bi1[t] = i1; bv2[t] = v2; bi2[t] = i2;
    }
    __syncthreads();
  }

  if (t < BM) {
    size_t o = (size_t)blockIdx.y * N + rowBase + t;
    pv1[o] = bv1[t]; pi1[o] = bi1[t]; pv2[o] = bv2[t]; pi2[o] = bi2[t];
  }
}

// ---------- kernel 3: merge chunk partials -> negative index ----------
__global__ void mergechunks_kernel(const float* __restrict__ pv1, const int* __restrict__ pi1,
                                   const float* __restrict__ pv2, const int* __restrict__ pi2,
                                   int* __restrict__ negIdx) {
  int row = blockIdx.x * 256 + threadIdx.x;
  float v1 = INFINITY, v2 = INFINITY;
  int i1 = 0x7fffffff, i2 = 0x7fffffff;
#pragma unroll
  for (int c = 0; c < NCHUNK; ++c) {
    size_t o = (size_t)c * N + row;
    mergePair(v1, i1, v2, i2, pv1[o], pi1[o], pv2[o], pi2[o]);
  }
  negIdx[row] = i2;   // 2nd-smallest among j != i  ==  reference idx3[:,2]
}

// ---------- kernel 4: per-row triplet hinge ----------
__global__ void finish_kernel(const float* __restrict__ A, const float* __restrict__ P,
                              const int* __restrict__ negIdx, float* __restrict__ rowLoss) {
  int row  = blockIdx.x * 4 + (threadIdx.x >> 6);
  int lane = threadIdx.x & 63;
  int nr = negIdx[row];
  float4 av = ((const float4*)(A + (size_t)row * D))[lane];
  float4 pv = ((const float4*)(P + (size_t)row * D))[lane];
  float4 gv = ((const float4*)(A + (size_t)nr  * D))[lane];
  float dap = 0.f, dan = 0.f, x;
  x = av.x - pv.x + EPS_PAIR; dap += x * x;
  x = av.y - pv.y + EPS_PAIR; dap += x * x;
  x = av.z - pv.z + EPS_PAIR; dap += x * x;
  x = av.w - pv.w + EPS_PAIR; dap += x * x;
  x = av.x - gv.x + EPS_PAIR; dan += x * x;
  x = av.y - gv.y + EPS_PAIR; dan += x * x;
  x = av.z - gv.z + EPS_PAIR; dan += x * x;
  x = av.w - gv.w + EPS_PAIR; dan += x * x;
#pragma unroll
  for (int m = 32; m; m >>= 1) {
    dap += __shfl_xor(dap, m);
    dan += __shfl_xor(dan, m);
  }
  if (lane == 0)
    rowLoss[row] = fmaxf(sqrtf(dap) - sqrtf(dan) + MARGIN, 0.f);
}

// ---------- kernel 5: deterministic mean reduction ----------
__global__ void reduce_kernel(const float* __restrict__ rowLoss, float* __restrict__ out) {
  __shared__ float smem[256];
  int t = threadIdx.x;
  float s = 0.f;
  for (int i = t; i < N; i += 256) s += rowLoss[i];
  smem[t] = s;
  __syncthreads();
  for (int stride = 128; stride; stride >>= 1) {
    if (t < stride) smem[t] += smem[t + stride];
    __syncthreads();
  }
  if (t == 0) out[0] = smem[0] * (1.0f / (float)N);
}

// ---------- launch ----------
extern "C" void kernel_launch(void* const* d_in, const int* in_sizes, int n_in,
                              void* d_out, int out_size, void* d_ws, size_t ws_size,
                              hipStream_t stream) {
  const float* inputs   = (const float*)d_in[0];
  const float* positive = (const float*)d_in[1];
  float* out = (float*)d_out;

  // ws layout (all 4B types; ~8.9 MB total)
  float* inputsT = (float*)d_ws;               // N*D
  float* sq      = inputsT + (size_t)N * D;    // N
  float* pv1     = sq + N;                     // NCHUNK*N
  float* pv2     = pv1 + (size_t)NCHUNK * N;   // NCHUNK*N
  int*   pi1     = (int*)(pv2 + (size_t)NCHUNK * N);  // NCHUNK*N
  int*   pi2     = pi1 + (size_t)NCHUNK * N;   // NCHUNK*N
  int*   negIdx  = pi2 + (size_t)NCHUNK * N;   // N
  float* rowLoss = (float*)(negIdx + N);       // N

  transpose_kernel<<<dim3(N / 32, D / 32), dim3(32, 8), 0, stream>>>(inputs, inputsT);
  rowsq_kernel<<<N / 4, 256, 0, stream>>>(inputs, sq);
  neighbor_kernel<<<dim3(N / BM, NCHUNK), NTHREADS, 0, stream>>>(inputs, inputsT, sq,
                                                                 pv1, pi1, pv2, pi2);
  mergechunks_kernel<<<N / 256, 256, 0, stream>>>(pv1, pi1, pv2, pi2, negIdx);
  finish_kernel<<<N / 4, 256, 0, stream>>>(inputs, positive, negIdx, rowLoss);
  reduce_kernel<<<1, 256, 0, stream>>>(rowLoss, out);
}

// Round 2
// 106.102 us; speedup vs baseline: 5.4737x; 5.4737x over previous
//
#include <hip/hip_runtime.h>
#include <math.h>

#define N 8192
#define D 256
#define NCH 16                 // column chunks (grid.y)
#define RB 256                 // rows per block (4 waves x 64)
#define RT 4                   // row-tiles (16 rows) per wave
#define CHUNK (N / NCH)        // 512 cols per block
#define NCT (CHUNK / 16)       // 32 col-tiles of 16

constexpr float MARGIN = 0.3f;
constexpr float EPS_PAIR = 1e-6f;

typedef float f32x4 __attribute__((ext_vector_type(4)));
typedef short s16x8 __attribute__((ext_vector_type(8)));

// ---------- helpers ----------
__device__ __forceinline__ bool lessVI(float v, int i, float w, int j) {
  return (v < w) || (v == w && i < j);
}

__device__ __forceinline__ void mergePair(float& v1, int& i1, float& v2, int& i2,
                                          float w1, int q1, float w2, int q2) {
  if (lessVI(w1, q1, v1, i1)) {
    bool b = lessVI(v1, i1, w2, q2);
    float nv2 = b ? v1 : w2;
    int   ni2 = b ? i1 : q2;
    v1 = w1; i1 = q1; v2 = nv2; i2 = ni2;
  } else if (lessVI(w1, q1, v2, i2)) {
    v2 = w1; i2 = q1;
  }
}

__device__ __forceinline__ short bf16rne(float x) {
  unsigned u = __float_as_uint(x);
  unsigned r = (u + 0x7FFFu + ((u >> 16) & 1u)) >> 16;
  return (short)r;
}

__device__ __forceinline__ void load_lds16(const void* g, void* l) {
  __builtin_amdgcn_global_load_lds((const __attribute__((address_space(1))) void*)g,
                                   (__attribute__((address_space(3))) void*)l, 16, 0, 0);
}

// ---------- kernel 0: fp32 -> bf16 (RNE) ----------
__global__ void convert_kernel(const float* __restrict__ in, short* __restrict__ outb) {
  int i = (blockIdx.x * 256 + threadIdx.x) * 8;
  float4 a = *(const float4*)(in + i);
  float4 b = *(const float4*)(in + i + 4);
  s16x8 r;
  r[0] = bf16rne(a.x); r[1] = bf16rne(a.y); r[2] = bf16rne(a.z); r[3] = bf16rne(a.w);
  r[4] = bf16rne(b.x); r[5] = bf16rne(b.y); r[6] = bf16rne(b.z); r[7] = bf16rne(b.w);
  *(s16x8*)(outb + i) = r;
}

// ---------- kernel 1: row squared norms (fp32, from original inputs) ----------
__global__ void rowsq_kernel(const float* __restrict__ in, float* __restrict__ sq) {
  int row  = blockIdx.x * 4 + (threadIdx.x >> 6);
  int lane = threadIdx.x & 63;
  float4 v = ((const float4*)(in + (size_t)row * D))[lane];
  float s = v.x * v.x + v.y * v.y + v.z * v.z + v.w * v.w;
#pragma unroll
  for (int m = 32; m; m >>= 1) s += __shfl_xor(s, m);
  if (lane == 0) sq[row] = s;
}

// ---------- kernel 2: MFMA Gram + per-row top-2-min (partial per column chunk) ----------
__global__ __launch_bounds__(256, 2) void neighbor_kernel(
    const short* __restrict__ Abf, const float* __restrict__ sq,
    float* __restrict__ pv1, int* __restrict__ pi1,
    float* __restrict__ pv2, int* __restrict__ pi2) {
  __shared__ __attribute__((aligned(16))) char ldsB[2][8192];

  const int t = threadIdx.x;
  const int lane = t & 63;
  const int wave = t >> 6;
  const int rowBase = blockIdx.x * RB + wave * 64;   // this wave's 64 rows
  const int colBase = blockIdx.y * CHUNK;

  const int lrow = lane & 15;    // fragment row (A) / col (B) within 16-tile
  const int lkg  = lane >> 4;    // k-group 0..3

  // ---- A fragments for 4 row-tiles x 8 k-steps, held in registers (128 VGPRs)
  s16x8 afrag[RT][8];
#pragma unroll
  for (int rt = 0; rt < RT; ++rt) {
    const short* arow = Abf + (size_t)(rowBase + rt * 16 + lrow) * D;
#pragma unroll
    for (int ks = 0; ks < 8; ++ks)
      afrag[rt][ks] = *(const s16x8*)(arow + ks * 32 + lkg * 8);
  }

  // ---- per-(lane,row) running top-2 (indices packed 16+16)
  float v1[RT][4], v2[RT][4];
  unsigned i12[RT][4];
#pragma unroll
  for (int rt = 0; rt < RT; ++rt)
#pragma unroll
    for (int q = 0; q < 4; ++q) { v1[rt][q] = INFINITY; v2[rt][q] = INFINITY; i12[rt][q] = 0xFFFFFFFFu; }

  // ---- stage col-tile ct into buf: LDS linear dest, inverse-swizzled global src
  auto stage = [&](int buf, int ct) {
#pragma unroll
    for (int q = 0; q < 2; ++q) {
      int p = (wave * 2 + q) * 1024 + lane * 16;  // linear LDS byte position
      int r = p >> 9;                             // B row 0..15
      int o = p & 511;                            // within-row byte
      const char* src = (const char*)Abf +
          (size_t)(colBase + ct * 16 + r) * (D * 2) + (o ^ ((r & 7) << 4));
      load_lds16(src, &ldsB[buf][(wave * 2 + q) * 1024]);
    }
  };

  stage(0, 0);
  __syncthreads();

  for (int ct = 0; ct < NCT; ++ct) {
    if (ct + 1 < NCT) stage((ct + 1) & 1, ct + 1);

    const char* bt = ldsB[ct & 1];
    f32x4 acc[RT];
#pragma unroll
    for (int rt = 0; rt < RT; ++rt) acc[rt] = (f32x4){0.f, 0.f, 0.f, 0.f};

#pragma unroll
    for (int ks = 0; ks < 8; ++ks) {
      int off = (ks * 64 + lkg * 16) ^ ((lrow & 7) << 4);   // swizzled read
      s16x8 bfrag = *(const s16x8*)(bt + lrow * 512 + off);
#pragma unroll
      for (int rt = 0; rt < RT; ++rt)
        acc[rt] = __builtin_amdgcn_mfma_f32_16x16x32_bf16(afrag[rt][ks], bfrag, acc[rt], 0, 0, 0);
    }

    // selection: score = sq[j] - 2*G[i][j]  (monotone in dist^2 per row)
    int j = colBase + ct * 16 + lrow;
    float sqj = sq[j];
#pragma unroll
    for (int rt = 0; rt < RT; ++rt) {
#pragma unroll
      for (int q = 0; q < 4; ++q) {
        float s = fmaf(-2.f, acc[rt][q], sqj);
        int ig = rowBase + rt * 16 + lkg * 4 + q;
        if (j == ig) s = INFINITY;            // exclude self
        float ov1 = v1[rt][q];
        bool b1 = s < ov1;
        bool b2 = s < v2[rt][q];
        v2[rt][q] = b1 ? ov1 : (b2 ? s : v2[rt][q]);
        v1[rt][q] = b1 ? s : ov1;
        unsigned o12 = i12[rt][q];
        i12[rt][q] = b1 ? (((unsigned)j << 16) | (o12 >> 16))
                        : (b2 ? ((o12 & 0xFFFF0000u) | (unsigned)j) : o12);
      }
    }
    __syncthreads();
  }

  // ---- cross-lane merge over the 16 lanes holding the same row, then write partials
#pragma unroll
  for (int rt = 0; rt < RT; ++rt) {
#pragma unroll
    for (int q = 0; q < 4; ++q) {
      float a1 = v1[rt][q], a2 = v2[rt][q];
      int j1 = (int)(i12[rt][q] >> 16), j2 = (int)(i12[rt][q] & 0xFFFFu);
#pragma unroll
      for (int m = 1; m < 16; m <<= 1) {
        float w1 = __shfl_xor(a1, m); int p1 = __shfl_xor(j1, m);
        float w2 = __shfl_xor(a2, m); int p2 = __shfl_xor(j2, m);
        mergePair(a1, j1, a2, j2, w1, p1, w2, p2);
      }
      if ((lane & 15) == 0) {
        int ig = rowBase + rt * 16 + lkg * 4 + q;
        size_t o = (size_t)blockIdx.y * N + ig;
        pv1[o] = a1; pi1[o] = j1; pv2[o] = a2; pi2[o] = j2;
      }
    }
  }
}

// ---------- kernel 3: merge chunk partials -> negative index ----------
__global__ void mergechunks_kernel(const float* __restrict__ pv1, const int* __restrict__ pi1,
                                   const float* __restrict__ pv2, const int* __restrict__ pi2,
                                   int* __restrict__ negIdx) {
  int row = blockIdx.x * 256 + threadIdx.x;
  float v1 = INFINITY, v2 = INFINITY;
  int i1 = 0x7fffffff, i2 = 0x7fffffff;
#pragma unroll
  for (int c = 0; c < NCH; ++c) {
    size_t o = (size_t)c * N + row;
    mergePair(v1, i1, v2, i2, pv1[o], pi1[o], pv2[o], pi2[o]);
  }
  negIdx[row] = i2;   // 2nd-smallest among j != i  ==  reference idx3[:,2]
}

// ---------- kernel 4: per-row triplet hinge (fp32, original inputs) ----------
__global__ void finish_kernel(const float* __restrict__ A, const float* __restrict__ P,
                              const int* __restrict__ negIdx, float* __restrict__ rowLoss) {
  int row  = blockIdx.x * 4 + (threadIdx.x >> 6);
  int lane = threadIdx.x & 63;
  int nr = negIdx[row];
  float4 av = ((const float4*)(A + (size_t)row * D))[lane];
  float4 pv = ((const float4*)(P + (size_t)row * D))[lane];
  float4 gv = ((const float4*)(A + (size_t)nr  * D))[lane];
  float dap = 0.f, dan = 0.f, x;
  x = av.x - pv.x + EPS_PAIR; dap += x * x;
  x = av.y - pv.y + EPS_PAIR; dap += x * x;
  x = av.z - pv.z + EPS_PAIR; dap += x * x;
  x = av.w - pv.w + EPS_PAIR; dap += x * x;
  x = av.x - gv.x + EPS_PAIR; dan += x * x;
  x = av.y - gv.y + EPS_PAIR; dan += x * x;
  x = av.z - gv.z + EPS_PAIR; dan += x * x;
  x = av.w - gv.w + EPS_PAIR; dan += x * x;
#pragma unroll
  for (int m = 32; m; m >>= 1) {
    dap += __shfl_xor(dap, m);
    dan += __shfl_xor(dan, m);
  }
  if (lane == 0)
    rowLoss[row] = fmaxf(sqrtf(dap) - sqrtf(dan) + MARGIN, 0.f);
}

// ---------- kernel 5: deterministic mean reduction ----------
__global__ void reduce_kernel(const float* __restrict__ rowLoss, float* __restrict__ out) {
  __shared__ float smem[256];
  int t = threadIdx.x;
  float s = 0.f;
  for (int i = t; i < N; i += 256) s += rowLoss[i];
  smem[t] = s;
  __syncthreads();
  for (int stride = 128; stride; stride >>= 1) {
    if (t < stride) smem[t] += smem[t + stride];
    __syncthreads();
  }
  if (t == 0) out[0] = smem[0] * (1.0f / (float)N);
}

// ---------- launch ----------
extern "C" void kernel_launch(void* const* d_in, const int* in_sizes, int n_in,
                              void* d_out, int out_size, void* d_ws, size_t ws_size,
                              hipStream_t stream) {
  const float* inputs   = (const float*)d_in[0];
  const float* positive = (const float*)d_in[1];
  float* out = (float*)d_out;

  // ws layout (~6.3 MB)
  short* Abf     = (short*)d_ws;                       // N*D bf16 (4 MB)
  float* sq      = (float*)(Abf + (size_t)N * D);      // N
  float* pv1     = sq + N;                             // NCH*N
  float* pv2     = pv1 + (size_t)NCH * N;              // NCH*N
  int*   pi1     = (int*)(pv2 + (size_t)NCH * N);      // NCH*N
  int*   pi2     = pi1 + (size_t)NCH * N;              // NCH*N
  int*   negIdx  = pi2 + (size_t)NCH * N;              // N
  float* rowLoss = (float*)(negIdx + N);               // N

  convert_kernel<<<(N * D) / (256 * 8), 256, 0, stream>>>(inputs, Abf);
  rowsq_kernel<<<N / 4, 256, 0, stream>>>(inputs, sq);
  neighbor_kernel<<<dim3(N / RB, NCH), 256, 0, stream>>>(Abf, sq, pv1, pi1, pv2, pi2);
  mergechunks_kernel<<<N / 256, 256, 0, stream>>>(pv1, pi1, pv2, pi2, negIdx);
  finish_kernel<<<N / 4, 256, 0, stream>>>(inputs, positive, negIdx, rowLoss);
  reduce_kernel<<<1, 256, 0, stream>>>(rowLoss, out);
}

// Round 4
// 66.007 us; speedup vs baseline: 8.7987x; 1.6075x over previous
//
#include <hip/hip_runtime.h>
#include <math.h>

#define N 8192
#define D 256
#define NCH 16                 // column chunks (grid.y)
#define RB 128                 // rows per block (4 waves x 32)
#define RT 2                   // row-tiles (16 rows) per wave
#define CHUNK (N / NCH)        // 512 cols per chunk
#define NCT (CHUNK / 16)       // 32 col-tiles of 16

constexpr float MARGIN = 0.3f;
constexpr float EPS_PAIR = 1e-6f;
constexpr float BIAS = 512.0f;   // makes all scores positive -> asuint monotone

typedef float f32x4 __attribute__((ext_vector_type(4)));
typedef short s16x8 __attribute__((ext_vector_type(8)));
typedef short s16x4 __attribute__((ext_vector_type(4)));

// ---------- helpers ----------
__device__ __forceinline__ short bf16rne(float x) {
  unsigned u = __float_as_uint(x);
  unsigned r = (u + 0x7FFFu + ((u >> 16) & 1u)) >> 16;
  return (short)r;
}

__device__ __forceinline__ void load_lds16(const void* g, void* l) {
  __builtin_amdgcn_global_load_lds((const __attribute__((address_space(1))) void*)g,
                                   (__attribute__((address_space(3))) void*)l, 16, 0, 0);
}

// merge sorted pair (w1<=w2) into sorted running top-2 (v1<=v2), all packed u32
__device__ __forceinline__ void top2merge(unsigned& v1, unsigned& v2,
                                          unsigned w1, unsigned w2) {
  unsigned mx = v1 > w1 ? v1 : w1;
  v1 = v1 < w1 ? v1 : w1;
  unsigned mn = v2 < w2 ? v2 : w2;
  v2 = mx < mn ? mx : mn;
}

// ---------- kernel 0: fused bf16 convert + biased row squared norms ----------
__global__ void prep_kernel(const float* __restrict__ in, short* __restrict__ Abf,
                            float* __restrict__ sq512) {
  int row  = blockIdx.x * 4 + (threadIdx.x >> 6);
  int lane = threadIdx.x & 63;
  float4 v = ((const float4*)(in + (size_t)row * D))[lane];
  s16x4 b;
  b[0] = bf16rne(v.x); b[1] = bf16rne(v.y); b[2] = bf16rne(v.z); b[3] = bf16rne(v.w);
  *(s16x4*)(Abf + (size_t)row * D + lane * 4) = b;
  float s = v.x * v.x + v.y * v.y + v.z * v.z + v.w * v.w;
#pragma unroll
  for (int m = 32; m; m >>= 1) s += __shfl_xor(s, m);
  if (lane == 0) sq512[row] = s + BIAS;
}

// ---------- kernel 1: MFMA Gram + packed-u32 per-row top-2-min (per chunk) ----------
__global__ __launch_bounds__(256, 3) void neighbor_kernel(
    const short* __restrict__ Abf, const float* __restrict__ sq512,
    uint2* __restrict__ pp) {
  __shared__ __attribute__((aligned(16))) char ldsB[2][8192];

  const int t = threadIdx.x;
  const int lane = t & 63;
  const int wave = t >> 6;
  const int rowBase = blockIdx.x * RB + wave * 32;   // this wave's 32 rows
  const int colBase = blockIdx.y * CHUNK;

  const int lrow = lane & 15;    // fragment row (A) / col (B) within 16-tile
  const int lkg  = lane >> 4;    // k-group 0..3

  // ---- A fragments: 2 row-tiles x 8 k-steps (64 VGPRs)
  s16x8 afrag[RT][8];
#pragma unroll
  for (int rt = 0; rt < RT; ++rt) {
    const short* arow = Abf + (size_t)(rowBase + rt * 16 + lrow) * D;
#pragma unroll
    for (int ks = 0; ks < 8; ++ks)
      afrag[rt][ks] = *(const s16x8*)(arow + ks * 32 + lkg * 8);
  }

  // ---- packed running top-2 per (rt,q): score19 | idx13
  unsigned v1[RT][4], v2[RT][4];
#pragma unroll
  for (int rt = 0; rt < RT; ++rt)
#pragma unroll
    for (int q = 0; q < 4; ++q) { v1[rt][q] = 0xFFFFFFFFu; v2[rt][q] = 0xFFFFFFFFu; }

  // ---- stage col-tile ct: LDS linear dest, inverse-swizzled global src
  auto stage = [&](int buf, int ct) {
#pragma unroll
    for (int q = 0; q < 2; ++q) {
      int p = (wave * 2 + q) * 1024 + lane * 16;  // linear LDS byte position
      int r = p >> 9;                             // B row 0..15
      int o = p & 511;                            // within-row byte
      const char* src = (const char*)Abf +
          (size_t)(colBase + ct * 16 + r) * (D * 2) + (o ^ ((r & 7) << 4));
      load_lds16(src, &ldsB[buf][(wave * 2 + q) * 1024]);
    }
  };

  stage(0, 0);
  __syncthreads();

  for (int ct = 0; ct < NCT; ++ct) {
    if (ct + 1 < NCT) stage((ct + 1) & 1, ct + 1);

    const int j = colBase + ct * 16 + lrow;
    const float sqjp = sq512[j];          // sq[j] + BIAS, issued early

    const char* bt = ldsB[ct & 1];
    f32x4 acc[RT];
#pragma unroll
    for (int rt = 0; rt < RT; ++rt) acc[rt] = (f32x4){0.f, 0.f, 0.f, 0.f};

#pragma unroll
    for (int ks = 0; ks < 8; ++ks) {
      int off = (ks * 64 + lkg * 16) ^ ((lrow & 7) << 4);   // swizzled read
      s16x8 bfrag = *(const s16x8*)(bt + lrow * 512 + off);
#pragma unroll
      for (int rt = 0; rt < RT; ++rt)
        acc[rt] = __builtin_amdgcn_mfma_f32_16x16x32_bf16(afrag[rt][ks], bfrag, acc[rt], 0, 0, 0);
    }

#pragma unroll
    for (int rt = 0; rt < RT; ++rt) {
      const bool diag = (colBase + ct * 16) == (rowBase + rt * 16);  // wave-uniform
#pragma unroll
      for (int q = 0; q < 4; ++q) {
        float s = fmaf(-2.f, acc[rt][q], sqjp);       // dist^2 - sq[i] + BIAS > 0
        unsigned p = (__float_as_uint(s) & 0xFFFFE000u) | (unsigned)j;
        if (diag) p = (lrow == lkg * 4 + q) ? 0xFFFFFFFFu : p;  // exclude self
        unsigned mx = v1[rt][q] > p ? v1[rt][q] : p;
        v1[rt][q] = v1[rt][q] < p ? v1[rt][q] : p;
        v2[rt][q] = v2[rt][q] < mx ? v2[rt][q] : mx;
      }
    }
    __syncthreads();
  }

  // ---- cross-lane merge over the 16 lanes sharing a row, write partials
#pragma unroll
  for (int rt = 0; rt < RT; ++rt) {
#pragma unroll
    for (int q = 0; q < 4; ++q) {
      unsigned a1 = v1[rt][q], a2 = v2[rt][q];
#pragma unroll
      for (int m = 1; m < 16; m <<= 1) {
        unsigned w1 = (unsigned)__shfl_xor((int)a1, m);
        unsigned w2 = (unsigned)__shfl_xor((int)a2, m);
        top2merge(a1, a2, w1, w2);
      }
      if (lrow == 0) {
        int ig = rowBase + rt * 16 + lkg * 4 + q;
        pp[(size_t)blockIdx.y * N + ig] = make_uint2(a1, a2);
      }
    }
  }
}

// ---------- kernel 2: fused chunk-merge + triplet hinge ----------
__global__ void finish_kernel(const float* __restrict__ A, const float* __restrict__ P,
                              const uint2* __restrict__ pp, float* __restrict__ rowLoss) {
  int row  = blockIdx.x * 4 + (threadIdx.x >> 6);
  int lane = threadIdx.x & 63;

  // merge the 16 chunk partials (lanes replicated x4, all compute same result)
  uint2 pr = pp[(size_t)(lane & 15) * N + row];
  unsigned a1 = pr.x, a2 = pr.y;
#pragma unroll
  for (int m = 1; m < 16; m <<= 1) {
    unsigned w1 = (unsigned)__shfl_xor((int)a1, m);
    unsigned w2 = (unsigned)__shfl_xor((int)a2, m);
    top2merge(a1, a2, w1, w2);
  }
  int nr = (int)(a2 & 0x1FFFu);   // 2nd-smallest among j != i == reference idx3[:,2]

  float4 av = ((const float4*)(A + (size_t)row * D))[lane];
  float4 pv = ((const float4*)(P + (size_t)row * D))[lane];
  float4 gv = ((const float4*)(A + (size_t)nr  * D))[lane];
  float dap = 0.f, dan = 0.f, x;
  x = av.x - pv.x + EPS_PAIR; dap += x * x;
  x = av.y - pv.y + EPS_PAIR; dap += x * x;
  x = av.z - pv.z + EPS_PAIR; dap += x * x;
  x = av.w - pv.w + EPS_PAIR; dap += x * x;
  x = av.x - gv.x + EPS_PAIR; dan += x * x;
  x = av.y - gv.y + EPS_PAIR; dan += x * x;
  x = av.z - gv.z + EPS_PAIR; dan += x * x;
  x = av.w - gv.w + EPS_PAIR; dan += x * x;
#pragma unroll
  for (int m = 32; m; m >>= 1) {
    dap += __shfl_xor(dap, m);
    dan += __shfl_xor(dan, m);
  }
  if (lane == 0)
    rowLoss[row] = fmaxf(sqrtf(dap) - sqrtf(dan) + MARGIN, 0.f);
}

// ---------- kernel 3: deterministic mean reduction ----------
__global__ void reduce_kernel(const float* __restrict__ rowLoss, float* __restrict__ out) {
  __shared__ float smem[256];
  int t = threadIdx.x;
  float s = 0.f;
  for (int i = t; i < N; i += 256) s += rowLoss[i];
  smem[t] = s;
  __syncthreads();
  for (int stride = 128; stride; stride >>= 1) {
    if (t < stride) smem[t] += smem[t + stride];
    __syncthreads();
  }
  if (t == 0) out[0] = smem[0] * (1.0f / (float)N);
}

// ---------- launch ----------
extern "C" void kernel_launch(void* const* d_in, const int* in_sizes, int n_in,
                              void* d_out, int out_size, void* d_ws, size_t ws_size,
                              hipStream_t stream) {
  const float* inputs   = (const float*)d_in[0];
  const float* positive = (const float*)d_in[1];
  float* out = (float*)d_out;

  // ws layout (~5.1 MB)
  short* Abf     = (short*)d_ws;                       // N*D bf16 (4 MB)
  float* sq512   = (float*)(Abf + (size_t)N * D);      // N
  uint2* pp      = (uint2*)(sq512 + N);                // NCH*N uint2 (1 MB)
  float* rowLoss = (float*)(pp + (size_t)NCH * N);     // N

  prep_kernel<<<N / 4, 256, 0, stream>>>(inputs, Abf, sq512);
  neighbor_kernel<<<dim3(N / RB, NCH), 256, 0, stream>>>(Abf, sq512, pp);
  finish_kernel<<<N / 4, 256, 0, stream>>>(inputs, positive, pp, rowLoss);
  reduce_kernel<<<1, 256, 0, stream>>>(rowLoss, out);
}